// Round 5
// baseline (1267.012 us; speedup 1.0000x reference)
//
#include <hip/hip_runtime.h>
#include <hip/hip_bf16.h>

#define HW2D 65536
#define NPIX 524288   // 8 * 65536
#define NB 8
#define PW 258
#define PP 66564      // 258*258
#define NSTEPS 16
#define OFF9(s) (((s)/3 - 1)*PW + ((s)%3 - 1))

typedef __hip_bfloat16 bf16;
typedef unsigned long long u64;
typedef __attribute__((ext_vector_type(8))) short short8;
typedef __attribute__((ext_vector_type(4))) float f32x4;

__device__ __forceinline__ unsigned short f2bfu(float v){
  bf16 h = __float2bfloat16(v); return *(unsigned short*)&h;
}
__device__ __forceinline__ float fast_tanh(float z){
  float az = fabsf(z);
  float e = __expf(2.0f*az);
  float t = 1.0f - 2.0f/(e+1.0f);
  return copysignf(t, z);
}
__device__ __forceinline__ float fast_sigmoid(float z){
  return 1.0f/(1.0f + __expf(-z));
}
__device__ __forceinline__ unsigned char f2fp8(float v){
  return (unsigned char)(__builtin_amdgcn_cvt_pk_fp8_f32(v, 0.f, 0, false) & 0xFF);
}
// HH record layout: byte m <-> channel ch(m) = (m>>1) + (m&1)*16
__device__ __forceinline__ int chmap(int m){ return (m>>1) + (m&1)*16; }

// accum: [0..15] per-step diff2, [16] norm, [17] pw, [18] sat, [19] leak,
// [20] cos_a, [21] sin_a, [22] decay
__global__ void k_prep(const float* angle, const float* decay_logit, float* accum){
  int t = threadIdx.x;
  if (t < 20) accum[t] = 0.0f;
  if (t == 0){
    float ang = tanhf(angle[0])*0.02f;
    accum[20] = cosf(ang);
    accum[21] = sinf(ang);
    accum[22] = 0.95f + 0.05f/(1.0f+expf(-decay_logit[0]));
  }
}

// WB8: fp8 A-operand weight fragments (A row = lane&15 = oc_low, k = g*8+j).
// slots 0-8: tile0 (oc 0-15) taps 0-8; 9-17: tile1 (oc 16-31); 18: gate row
// (row 0 = w_gate over hh channels; other rows zero).
// K-index maps to interleaved HH byte: ch = chmap(g*8+j).
// Center tap (s=4): +0.8 on oc==ch diagonal (folds 0.8*hh_old).
// WB16: bf16 A-operand tail fragments. k<16 -> tapA ch k; k>=16 -> tapB.
// slots 0-4: tile0 pair-steps; 5-9: tile1; 10: gate row (center-tap tail).
__global__ void k_wprep(const float* __restrict__ w_up, const float* __restrict__ w_gate,
                        u64* __restrict__ WB8, short8* __restrict__ WB16){
  int t = threadIdx.x;
  int lane = t & 63;
  int r_ = lane & 15, g = lane >> 4;
  for (int slot = t>>6; slot < 19; slot += 4){
    u64 v = 0;
    #pragma unroll
    for (int j=0;j<8;j++){
      float w = 0.f;
      int ch = chmap(g*8+j);
      if (slot < 18){
        int tile = slot/9, s = slot%9;
        int oc = tile*16 + r_;
        int dy=s/3, dx=s%3;
        w = w_up[((oc*42+ch)*3+dy)*3+dx];
        if (s==4 && oc==ch) w += 0.8f;
      } else {
        if (r_==0) w = w_gate[ch];
      }
      v |= ((u64)f2fp8(w)) << (8*j);
    }
    WB8[slot*64+lane] = v;
  }
  for (int slot = t>>6; slot < 11; slot += 4){
    short8 v;
    #pragma unroll
    for (int j=0;j<8;j++){
      float w = 0.f;
      int tt = (g&1)*8 + j;      // tail channel within tap
      int tapsel = g>>1;         // 0 = tapA, 1 = tapB
      if (slot < 10){
        int tile = slot/5, s2 = slot%5;
        int tap = 2*s2 + tapsel;
        int oc = tile*16 + r_;
        if (tap <= 8 && tt < 10){
          int src = (tt<4) ? (38+tt) : (32+(tt-4));
          int dy=tap/3, dx=tap%3;
          w = w_up[((oc*42+src)*3+dy)*3+dx];
        }
      } else {
        if (r_==0 && tapsel==0 && tt<10){
          int src = (tt<4) ? (38+tt) : (32+(tt-4));
          w = w_gate[src];
        }
      }
      v[j] = (short)f2bfu(w);
    }
    WB16[slot*64+lane] = v;
  }
}

__global__ void k_border(unsigned char* HH0, unsigned char* HH1, bf16* TAIL0, bf16* TAIL1){
  int i = blockIdx.x*256 + threadIdx.x;
  if (i >= NB*PP) return;
  int pp_ = i % PP;
  int r = pp_ / PW, c = pp_ % PW;
  if (r != 0 && r != 257 && c != 0 && c != 257) return;
  short8 z = (short8){0,0,0,0,0,0,0,0};
  ((short8*)HH0)[(size_t)i*2]   = z; ((short8*)HH0)[(size_t)i*2+1] = z;
  ((short8*)HH1)[(size_t)i*2]   = z; ((short8*)HH1)[(size_t)i*2+1] = z;
  ((short8*)TAIL0)[(size_t)i*2] = z; ((short8*)TAIL0)[(size_t)i*2+1] = z;
  ((short8*)TAIL1)[(size_t)i*2] = z; ((short8*)TAIL1)[(size_t)i*2+1] = z;
}

__global__ void k_init(const float* __restrict__ x, const float* __restrict__ w_in,
                       const float* __restrict__ b_in,
                       float2* __restrict__ S0, float2* __restrict__ F0,
                       float* __restrict__ WALL,
                       unsigned char* __restrict__ HH0, bf16* __restrict__ TAIL0,
                       bf16* __restrict__ TAIL1, float* accum){
  int tid = threadIdx.x;
  int p = blockIdx.x*256 + tid;
  int b = p >> 16, rem = p & 65535;
  int y = rem >> 8, xc = rem & 255;
  const float* xb = x + (size_t)b*6*HW2D;
  float wall = xb[rem];
  float fre = 1.0f - wall;
  float s_r = xb[HW2D + rem]*fre;
  float s_i = xb[2*HW2D + rem]*fre;
  S0[p] = (float2){s_r, s_i};
  F0[p] = (float2){s_r, s_i};
  WALL[p] = wall;
  float src10[10];
  src10[0]=wall;
  #pragma unroll
  for (int c=1;c<6;c++) src10[c]=xb[c*HW2D+rem];
  src10[6]=s_r; src10[7]=s_i; src10[8]=s_r; src10[9]=s_i;
  size_t padpix = (size_t)b*PP + (y+1)*PW + (xc+1);
  float hv[32];
  #pragma unroll
  for (int c=0;c<32;c++){
    float a = b_in[c];
    #pragma unroll
    for (int k=0;k<10;k++) a += w_in[c*10+k]*src10[k];
    hv[c] = fast_tanh(a)*fre;
  }
  // interleaved record: byte 4w+t: ch {2w, 16+2w, 2w+1, 17+2w}
  unsigned int words[8];
  #pragma unroll
  for (int w=0;w<8;w++){
    int lo = __builtin_amdgcn_cvt_pk_fp8_f32(hv[2*w], hv[16+2*w], 0, false);
    words[w] = (unsigned int)__builtin_amdgcn_cvt_pk_fp8_f32(hv[2*w+1], hv[17+2*w], lo, true);
  }
  uint4* hrec = (uint4*)(HH0 + padpix*32);
  hrec[0] = (uint4){words[0],words[1],words[2],words[3]};
  hrec[1] = (uint4){words[4],words[5],words[6],words[7]};
  unsigned short tv[16];
  tv[0]=f2bfu(s_r); tv[1]=f2bfu(s_i); tv[2]=f2bfu(s_r); tv[3]=f2bfu(s_i);
  #pragma unroll
  for (int c=0;c<6;c++) tv[4+c] = f2bfu(src10[c]);
  #pragma unroll
  for (int c=10;c<16;c++) tv[c] = 0;
  #pragma unroll
  for (int q=0;q<2;q++){
    short8 v;
    #pragma unroll
    for (int j=0;j<8;j++) v[j] = (short)tv[q*8+j];
    ((short8*)TAIL0)[padpix*2+q] = v;
    ((short8*)TAIL1)[padpix*2+q] = v;
  }
  float v = sqrtf(s_r*s_r + s_i*s_i);
  #pragma unroll
  for (int off=32; off>0; off>>=1) v += __shfl_down(v, off);
  __shared__ float red[4];
  int wid = tid >> 6;
  if ((tid&63)==0) red[wid] = v;
  __syncthreads();
  if (tid==0) atomicAdd(&accum[16], red[0]+red[1]+red[2]+red[3]);
}

// Fused step. Phase A: MFMA conv, weights as A-operand, activations as B.
// Output: row = oc (lane>>4*4+i), col = pixel (lane&15) -> per-thread 8
// channels of 4 pixels -> contiguous u64 stores into interleaved records.
__global__ __launch_bounds__(256) void k_step(
    const unsigned char* __restrict__ HHo, unsigned char* __restrict__ HHn,
    const bf16* __restrict__ TAILo, bf16* __restrict__ TAILn,
    const float2* __restrict__ So, float2* __restrict__ Sn,
    const float2* __restrict__ Fo, float2* __restrict__ Fn,
    const float* __restrict__ WALL,
    const u64* __restrict__ WB8, const short8* __restrict__ WB16,
    const float* __restrict__ b_up, const float* __restrict__ x,
    const float* __restrict__ b_gate, float* accum, int step){
  int bid = blockIdx.x;
  int b = bid & 7, y = bid >> 3;
  int tid = threadIdx.x;
  int wv = tid >> 6, lane = tid & 63;
  int r_ = lane & 15, g = lane >> 4;
  int bbase = b*PP;
  int rowbase = (y+1)*PW + 1;
  __shared__ float lgate[256];
  __shared__ float red[3][4];

  // ---- phase A ----
  int pix[4];
  #pragma unroll
  for (int mt=0;mt<4;mt++) pix[mt] = bbase + rowbase + wv*64 + mt*16 + r_;
  f32x4 acc[4][2], accg[4];
  #pragma unroll
  for (int mt=0;mt<4;mt++){
    acc[mt][0] = (f32x4){0.f,0.f,0.f,0.f};
    acc[mt][1] = (f32x4){0.f,0.f,0.f,0.f};
    accg[mt]   = (f32x4){0.f,0.f,0.f,0.f};
  }
  const u64* HH8 = (const u64*)HHo;
  const short8* T8 = (const short8*)TAILo;

  // seg1: 9 taps x 32 hh channels, fp8, 1-tap prefetch
  u64 aF[4], aN[4];
  #pragma unroll
  for (int mt=0;mt<4;mt++) aF[mt] = HH8[(size_t)(pix[mt]+OFF9(0))*4 + g];
  #pragma unroll
  for (int s=0;s<9;s++){
    if (s<8){
      #pragma unroll
      for (int mt=0;mt<4;mt++) aN[mt] = HH8[(size_t)(pix[mt]+OFF9(s+1))*4 + g];
    }
    u64 b0 = WB8[s*64+lane], b1 = WB8[(9+s)*64+lane];
    #pragma unroll
    for (int mt=0;mt<4;mt++){
      acc[mt][0] = __builtin_amdgcn_mfma_f32_16x16x32_fp8_fp8((long)b0, (long)aF[mt], acc[mt][0], 0,0,0);
      acc[mt][1] = __builtin_amdgcn_mfma_f32_16x16x32_fp8_fp8((long)b1, (long)aF[mt], acc[mt][1], 0,0,0);
    }
    if (s==4){
      u64 bg = WB8[18*64+lane];
      #pragma unroll
      for (int mt=0;mt<4;mt++)
        accg[mt] = __builtin_amdgcn_mfma_f32_16x16x32_fp8_fp8((long)bg, (long)aF[mt], accg[mt], 0,0,0);
    }
    if (s<8){
      #pragma unroll
      for (int mt=0;mt<4;mt++) aF[mt] = aN[mt];
    }
  }
  // seg2: 5 pair-steps x 16 tail channels, bf16, 1-step prefetch
  short8 tF[4], tN[4];
  {
    const int offA0 = OFF9(0), offB0 = OFF9(1);
    bool hiB = (g >= 2);
    #pragma unroll
    for (int mt=0;mt<4;mt++)
      tF[mt] = T8[(size_t)(pix[mt] + (hiB ? offB0 : offA0))*2 + (g&1)];
  }
  #pragma unroll
  for (int s2=0;s2<5;s2++){
    if (s2<4){
      const int tA = 2*(s2+1), tB = 2*(s2+1)+1;
      const int offA = OFF9(tA);
      const int offB = (tB <= 8) ? OFF9(tB) : 0;
      bool hiB = (g >= 2);
      #pragma unroll
      for (int mt=0;mt<4;mt++){
        int tp;
        if (tB <= 8) tp = pix[mt] + (hiB ? offB : offA);
        else         tp = hiB ? bbase : (pix[mt] + offA);
        tN[mt] = T8[(size_t)tp*2 + (g&1)];
      }
    }
    short8 b0 = WB16[s2*64+lane], b1 = WB16[(5+s2)*64+lane];
    #pragma unroll
    for (int mt=0;mt<4;mt++){
      acc[mt][0] = __builtin_amdgcn_mfma_f32_16x16x32_bf16(b0, tF[mt], acc[mt][0], 0,0,0);
      acc[mt][1] = __builtin_amdgcn_mfma_f32_16x16x32_bf16(b1, tF[mt], acc[mt][1], 0,0,0);
    }
    if (s2==2){
      short8 bgt = WB16[10*64+lane];
      #pragma unroll
      for (int mt=0;mt<4;mt++)
        accg[mt] = __builtin_amdgcn_mfma_f32_16x16x32_bf16(bgt, tF[mt], accg[mt], 0,0,0);
    }
    if (s2<4){
      #pragma unroll
      for (int mt=0;mt<4;mt++) tF[mt] = tN[mt];
    }
  }
  // gate redistribution: output row 0 = lanes g==0, i==0; col = pixel r_
  if (lane < 16){
    #pragma unroll
    for (int mt=0;mt<4;mt++) lgate[wv*64 + mt*16 + lane] = accg[mt][0];
  }

  // issue phase-B global loads (latency hidden under epilogue VALU)
  int p = b*HW2D + (y<<8) + tid;
  float2 sc = So[p];
  float2 fup = (y>0)    ? Fo[p-256] : (float2){0.f,0.f};
  float2 fdn = (y<255)  ? Fo[p+256] : (float2){0.f,0.f};
  float2 flt = (tid>0)  ? Fo[p-1]   : (float2){0.f,0.f};
  float2 frt = (tid<255)? Fo[p+1]   : (float2){0.f,0.f};
  float dlr = 0.f, dli = 0.f;
  if (step==8){
    const float* xb = x + (size_t)b*6*HW2D;
    int rem = (y<<8)+tid;
    dlr = xb[3*HW2D+rem]; dli = xb[4*HW2D+rem];
  }
  float wallB = WALL[p];

  // epilogue: hh_new = tanh(acc + bias)*free, 4 coalesced u64 stores/thread
  const float* wallrow = WALL + (size_t)b*HW2D + y*256;
  const float4* bup4 = (const float4*)b_up;
  float4 bb0 = bup4[g];      // b_up[4g..4g+3]
  float4 bb1 = bup4[4+g];    // b_up[16+4g..19+4g]
  #pragma unroll
  for (int mt=0;mt<4;mt++){
    float fre = 1.0f - wallrow[wv*64 + mt*16 + r_];
    float tA0 = fast_tanh(acc[mt][0][0] + bb0.x)*fre;
    float tB0 = fast_tanh(acc[mt][1][0] + bb1.x)*fre;
    float tA1 = fast_tanh(acc[mt][0][1] + bb0.y)*fre;
    float tB1 = fast_tanh(acc[mt][1][1] + bb1.y)*fre;
    float tA2 = fast_tanh(acc[mt][0][2] + bb0.z)*fre;
    float tB2 = fast_tanh(acc[mt][1][2] + bb1.z)*fre;
    float tA3 = fast_tanh(acc[mt][0][3] + bb0.w)*fre;
    float tB3 = fast_tanh(acc[mt][1][3] + bb1.w)*fre;
    int w0 = __builtin_amdgcn_cvt_pk_fp8_f32(tA0, tB0, 0, false);
    w0 = __builtin_amdgcn_cvt_pk_fp8_f32(tA1, tB1, w0, true);
    int w1 = __builtin_amdgcn_cvt_pk_fp8_f32(tA2, tB2, 0, false);
    w1 = __builtin_amdgcn_cvt_pk_fp8_f32(tA3, tB3, w1, true);
    *(uint2*)(HHn + (size_t)pix[mt]*32 + g*8) = (uint2){(unsigned)w0, (unsigned)w1};
  }
  __syncthreads();

  // ---- phase B ----
  float s_r = sc.x, s_i = sc.y;
  float incr = fup.x + fdn.x + flt.x + frt.x + dlr;
  float inci = fup.y + fdn.y + flt.y + frt.y + dli;
  float fre = 1.0f - wallB;
  float a = lgate[tid] + b_gate[0];
  float gg = 0.998f + 0.002f*fast_sigmoid(a);
  incr *= gg; inci *= gg;
  float ca = accum[20], sa = accum[21], dec = accum[22];
  float rr = incr*ca - inci*sa;
  float ri = incr*sa + inci*ca;
  incr = rr*fre; inci = ri*fre;
  float mag = sqrtf(incr*incr + inci*inci + 1e-8f);
  float sc2 = fminf(2.0f/mag, 1.0f);
  incr *= sc2; inci *= sc2;
  float pw = (fabsf(incr)+fabsf(inci))*wallB;
  float nr = dec*s_r + incr, ni = dec*s_i + inci;
  mag = sqrtf(nr*nr+ni*ni+1e-8f);
  sc2 = fminf(2.0f/mag, 1.0f);
  nr = nr*sc2*fre; ni = ni*sc2*fre;
  Sn[p] = (float2){nr, ni};
  Fn[p] = (float2){incr, inci};
  size_t padpix = (size_t)bbase + rowbase + tid;
  ushort4 pk;
  pk.x = f2bfu(nr); pk.y = f2bfu(ni); pk.z = f2bfu(incr); pk.w = f2bfu(inci);
  *(ushort4*)((unsigned short*)TAILn + padpix*16) = pk;
  float d2 = (nr-s_r)*(nr-s_r)+(ni-s_i)*(ni-s_i);
  float nrm = sqrtf(nr*nr+ni*ni);
  #pragma unroll
  for (int off=32; off>0; off>>=1){
    d2  += __shfl_down(d2, off);
    nrm += __shfl_down(nrm, off);
    pw  += __shfl_down(pw, off);
  }
  int wid = tid >> 6;
  if ((tid&63)==0){ red[0][wid]=d2; red[1][wid]=nrm; red[2][wid]=pw; }
  __syncthreads();
  if (tid==0){
    atomicAdd(&accum[step-1], red[0][0]+red[0][1]+red[0][2]+red[0][3]);
    atomicAdd(&accum[16],     red[1][0]+red[1][1]+red[1][2]+red[1][3]);
    atomicAdd(&accum[17],     red[2][0]+red[2][1]+red[2][2]+red[2][3]);
  }
}

__global__ void k_tail(const float* __restrict__ WALL, const float2* __restrict__ S,
                       float* accum){
  int tid = threadIdx.x;
  int p = blockIdx.x*256 + tid;
  float wall = WALL[p];
  float2 c = S[p];
  float vr = c.x, vi = c.y;
  float sat = (fabsf(vr)>4.0f ? 1.0f:0.0f) + (fabsf(vi)>4.0f ? 1.0f:0.0f);
  float nrm = sqrtf(vr*vr+vi*vi);
  float leak = (nrm>0.5f && wall>0.5f) ? 1.0f : 0.0f;
  #pragma unroll
  for (int off=32; off>0; off>>=1){
    sat  += __shfl_down(sat, off);
    leak += __shfl_down(leak, off);
  }
  __shared__ float red[2][4];
  int wid = tid >> 6;
  if ((tid&63)==0){ red[0][wid]=sat; red[1][wid]=leak; }
  __syncthreads();
  if (tid==0){
    atomicAdd(&accum[18], red[0][0]+red[0][1]+red[0][2]+red[0][3]);
    atomicAdd(&accum[19], red[1][0]+red[1][1]+red[1][2]+red[1][3]);
  }
}

__global__ void k_final(const float2* __restrict__ S, const int* __restrict__ target,
                        const float* __restrict__ accum, float* __restrict__ out){
  int t = threadIdx.x;
  if (t < 8){
    int ty = target[2*t], tx = target[2*t+1];
    int p = (t<<16) + (ty<<8) + tx;
    float2 c = S[p];
    float vr = c.x, vi = c.y;
    float mag = sqrtf(vr*vr+vi*vi+1e-8f);
    out[t*9] = (0.35f - mag)*12.0f;
    #pragma unroll
    for (int k=0;k<8;k++){
      float th = 6.283185307179586f * (float)k / 8.0f;
      out[t*9+1+k] = (vr*cosf(th)+vi*sinf(th) - 0.35f)*12.0f;
    }
  }
  if (t == 8){
    float d = 0.0f;
    for (int s=0;s<16;s++) d += sqrtf(accum[s]/1048576.0f);
    out[72] = d/16.0f;
    out[73] = accum[16]/8912896.0f;
    out[74] = accum[18]/1048576.0f;
    out[75] = accum[17]/(524288.0f*16.0f);
    out[76] = accum[19]/524288.0f;
  }
}

extern "C" void kernel_launch(void* const* d_in, const int* in_sizes, int n_in,
                              void* d_out, int out_size, void* d_ws, size_t ws_size,
                              hipStream_t stream) {
  const float* x       = (const float*)d_in[0];
  const int*   target  = (const int*)  d_in[1];
  const float* w_in    = (const float*)d_in[2];
  const float* b_in    = (const float*)d_in[3];
  const float* w_up    = (const float*)d_in[4];
  const float* b_up    = (const float*)d_in[5];
  const float* w_gate  = (const float*)d_in[6];
  const float* b_gate  = (const float*)d_in[7];
  const float* angle   = (const float*)d_in[8];
  const float* decay_l = (const float*)d_in[9];
  float* out = (float*)d_out;

  char* ws = (char*)d_ws;
  size_t off = 0;
  unsigned char* HH0 = (unsigned char*)(ws+off); off += (size_t)NB*PP*32;
  unsigned char* HH1 = (unsigned char*)(ws+off); off += (size_t)NB*PP*32;
  bf16* TAIL0=(bf16*)(ws+off); off += (size_t)NB*PP*32;
  bf16* TAIL1=(bf16*)(ws+off); off += (size_t)NB*PP*32;
  float2* S0 = (float2*)(ws+off); off += (size_t)NPIX*8;
  float2* S1 = (float2*)(ws+off); off += (size_t)NPIX*8;
  float2* F0 = (float2*)(ws+off); off += (size_t)NPIX*8;
  float2* F1 = (float2*)(ws+off); off += (size_t)NPIX*8;
  float* WALL = (float*)(ws+off); off += (size_t)NPIX*4;
  u64* WB8 = (u64*)(ws+off); off += (size_t)19*64*8;
  short8* WB16 = (short8*)(ws+off); off += (size_t)11*64*16;
  float* accum = (float*)(ws+off); off += 32*4;

  k_prep<<<1,32,0,stream>>>(angle, decay_l, accum);
  k_wprep<<<1,256,0,stream>>>(w_up, w_gate, WB8, WB16);
  k_border<<<(NB*PP+255)/256,256,0,stream>>>(HH0, HH1, TAIL0, TAIL1);
  k_init<<<NPIX/256,256,0,stream>>>(x, w_in, b_in, S0, F0, WALL, HH0, TAIL0, TAIL1, accum);

  unsigned char *hho=HH0, *hhn=HH1;
  bf16 *tlo=TAIL0, *tln=TAIL1;
  float2 *so=S0, *sn=S1, *fo=F0, *fn=F1;
  for (int t=1;t<=NSTEPS;t++){
    k_step<<<2048,256,0,stream>>>(hho, hhn, tlo, tln, so, sn, fo, fn, WALL,
                                  WB8, WB16, b_up, x, b_gate, accum, t);
    unsigned char* tc=hho; hho=hhn; hhn=tc;
    bf16* tb=tlo; tlo=tln; tln=tb;
    float2* tf=so; so=sn; sn=tf;
    tf=fo; fo=fn; fn=tf;
  }
  k_tail<<<NPIX/256,256,0,stream>>>(WALL, so, accum);
  k_final<<<1,64,0,stream>>>(so, target, accum, out);
}